// Round 5
// baseline (445.962 us; speedup 1.0000x reference)
//
#include <hip/hip_runtime.h>

typedef unsigned short u16;
typedef unsigned int u32;
typedef unsigned short u16x8 __attribute__((ext_vector_type(8)));
typedef __bf16 bf16x8 __attribute__((ext_vector_type(8)));
typedef float f32x4 __attribute__((ext_vector_type(4)));

#define QSCALE 0.18033688011112042f  /* 0.125 * log2(e) */

__device__ __forceinline__ u16 f2bf(float f) {
    unsigned u = __float_as_uint(f);
    u += 0x7fffu + ((u >> 16) & 1u);
    return (u16)(u >> 16);
}

__device__ __forceinline__ bf16x8 ldfrag(const u16* p) {
    return __builtin_bit_cast(bf16x8, *(const u16x8*)p);
}
__device__ __forceinline__ bf16x8 asbf(u16x8 v) {
    return __builtin_bit_cast(bf16x8, v);
}

__device__ __forceinline__ void async_cp16(const void* g, void* l) {
    __builtin_amdgcn_global_load_lds(
        (const __attribute__((address_space(1))) unsigned int*)g,
        (__attribute__((address_space(3))) unsigned int*)l, 16, 0, 0);
}

__device__ __forceinline__ uint2 pack4(float a, float b, float c, float d) {
    uint2 w;
    w.x = (u32)f2bf(a) | ((u32)f2bf(b) << 16);
    w.y = (u32)f2bf(c) | ((u32)f2bf(d) << 16);
    return w;
}

// ---------------- conversion kernels ----------------

__global__ void cvt_x(const float* __restrict__ x, u16* __restrict__ xb, int n4) {
    int i = blockIdx.x * blockDim.x + threadIdx.x;
    if (i < n4) {
        float4 v = ((const float4*)x)[i];
        ushort4 o;
        o.x = f2bf(v.x); o.y = f2bf(v.y); o.z = f2bf(v.z); o.w = f2bf(v.w);
        ((ushort4*)xb)[i] = o;
    }
}

__global__ __launch_bounds__(1024) void transp(const float* __restrict__ src, u16* __restrict__ dst) {
    __shared__ float t[32][33];
    int bx = blockIdx.x * 32, by = blockIdx.y * 32;
    t[threadIdx.y][threadIdx.x] = src[(by + threadIdx.y) * 1024 + bx + threadIdx.x];
    __syncthreads();
    dst[(bx + threadIdx.y) * 1024 + by + threadIdx.x] = f2bf(t[threadIdx.x][threadIdx.y]);
}

__global__ void mkbias(const float* __restrict__ bq, const float* __restrict__ bk,
                       const float* __restrict__ bv, float* __restrict__ bqkv) {
    int i = blockIdx.x * blockDim.x + threadIdx.x;
    if (i < 3072) bqkv[i] = (i < 1024) ? bq[i] : (i < 2048 ? bk[i - 1024] : bv[i - 2048]);
}

// ---------------- GEMM: C[M,N] = A[M,K] * Bt[N,K]^T + bias ----------------
// BK=64, unpadded [128][64] LDS tiles with XOR swizzle (group ^= row&7):
// conflict-free b128 frag reads, lane-contiguous global_load_lds staging,
// 32 MFMA per barrier-pair.
// EPI 0: Q/K projection, swapped mfma (C^T) -> packed dwordx2 to Qb/Kb
// EPI 1: V projection, normal operands -> packed dwordx2 to Vt [bh][dh][s]
// EPI 2: output projection, swapped -> float4 to outf

template <int EPI>
__global__ __launch_bounds__(256)
void gemm128(const u16* __restrict__ A, const u16* __restrict__ Bt,
             const float* __restrict__ bias,
             u16* __restrict__ Qb, u16* __restrict__ Kb, u16* __restrict__ Vt,
             float* __restrict__ outf) {
    __shared__ u16 Asm[128 * 64];
    __shared__ u16 Bsm[128 * 64];
    int tid = threadIdx.x;
    int wave = tid >> 6, lane = tid & 63;
    int lr = lane & 15, lq = lane >> 4;
    int wrow = (wave >> 1) * 64, wcol = (wave & 1) * 64;
    int tileM = blockIdx.y * 128, tileN = blockIdx.x * 128;

    f32x4 acc[4][4];
    for (int i = 0; i < 4; i++)
        for (int j = 0; j < 4; j++)
            acc[i][j] = (f32x4){0.f, 0.f, 0.f, 0.f};

    // staging map: LDS linear (tid*8 + rnd*2048) u16 -> row = rnd*32 + tid>>3,
    // group' = tid&7; holds global col-group g = g' ^ (row&7)
    int srow = tid >> 3;
    int sg = (tid & 7) ^ (srow & 7);
    const u16* ga = A + (tileM + srow) * 1024 + sg * 8;
    const u16* gb = Bt + (tileN + srow) * 1024 + sg * 8;
    u16* la = &Asm[tid * 8];
    u16* lb = &Bsm[tid * 8];

    // frag-read swizzle: want col-group ko*4+lq at row (..+lr): read g' = (ko*4+lq)^(lr&7)
    int sw0 = ((lq ^ (lr & 7)) << 3);          // ko=0
    int sw1 = (((4 + lq) ^ (lr & 7)) << 3);    // ko=1

    for (int k0 = 0; k0 < 1024; k0 += 64) {
        for (int rnd = 0; rnd < 4; rnd++) {
            async_cp16(ga + k0 + rnd * 32 * 1024, la + rnd * 2048);
            async_cp16(gb + k0 + rnd * 32 * 1024, lb + rnd * 2048);
        }
        __syncthreads();
        for (int ko = 0; ko < 2; ko++) {
            int sw = ko ? sw1 : sw0;
            bf16x8 af[4], bfr[4];
            for (int mt = 0; mt < 4; mt++) af[mt] = ldfrag(&Asm[(wrow + mt * 16 + lr) * 64 + sw]);
            for (int nt = 0; nt < 4; nt++) bfr[nt] = ldfrag(&Bsm[(wcol + nt * 16 + lr) * 64 + sw]);
            for (int mt = 0; mt < 4; mt++)
                for (int nt = 0; nt < 4; nt++) {
                    if (EPI == 1)
                        acc[mt][nt] = __builtin_amdgcn_mfma_f32_16x16x32_bf16(af[mt], bfr[nt], acc[mt][nt], 0, 0, 0);
                    else
                        acc[mt][nt] = __builtin_amdgcn_mfma_f32_16x16x32_bf16(bfr[nt], af[mt], acc[mt][nt], 0, 0, 0);
                }
        }
        __syncthreads();
    }

    if (EPI == 0) {
        for (int mt = 0; mt < 4; mt++) {
            int m = tileM + wrow + mt * 16 + lr;
            int b = m >> 11, s = m & 2047;
            for (int nt = 0; nt < 4; nt++) {
                int n0 = tileN + wcol + nt * 16 + lq * 4;   // [0,2048)
                float4 bn = *(const float4*)&bias[n0];
                int which = n0 >> 10, d = n0 & 1023, h = d >> 6, dh = d & 63;
                u16* dst = (which ? Kb : Qb) + ((b * 16 + h) * 2048 + s) * 64 + dh;
                f32x4 v = acc[mt][nt];
                uint2 w;
                if (which == 0)
                    w = pack4((v[0] + bn.x) * QSCALE, (v[1] + bn.y) * QSCALE,
                              (v[2] + bn.z) * QSCALE, (v[3] + bn.w) * QSCALE);
                else
                    w = pack4(v[0] + bn.x, v[1] + bn.y, v[2] + bn.z, v[3] + bn.w);
                *(uint2*)dst = w;
            }
        }
    } else if (EPI == 1) {
        for (int nt = 0; nt < 4; nt++) {
            int n0 = tileN + wcol + nt * 16 + lr;           // [0,1024) V-local
            float bn = bias[n0];                            // caller passed bias+2048
            int h = n0 >> 6, dh = n0 & 63;
            for (int mt = 0; mt < 4; mt++) {
                int m0 = tileM + wrow + mt * 16 + lq * 4;
                int b = m0 >> 11, s = m0 & 2047;
                f32x4 v = acc[mt][nt];
                uint2 w = pack4(v[0] + bn, v[1] + bn, v[2] + bn, v[3] + bn);
                *(uint2*)(Vt + ((b * 16 + h) * 64 + dh) * 2048 + s) = w;
            }
        }
    } else {
        for (int mt = 0; mt < 4; mt++) {
            int m = tileM + wrow + mt * 16 + lr;
            for (int nt = 0; nt < 4; nt++) {
                int n0 = tileN + wcol + nt * 16 + lq * 4;
                float4 bn = *(const float4*)&bias[n0];
                f32x4 v = acc[mt][nt];
                float4 st = {v[0] + bn.x, v[1] + bn.y, v[2] + bn.z, v[3] + bn.w};
                *(float4*)&outf[m * 1024 + n0] = st;
            }
        }
    }
}

// ---------------- flash attention ----------------
// Barrier-free: each wave owns 32 queries; K/V fragments loaded DIRECTLY from
// global into VGPRs (L1 serves the 4 waves' shared tile); LDS used only for
// the per-wave P C-layout->A-layout round-trip (lgkmcnt drain, no barrier).
__global__ __launch_bounds__(256)
void attn(const u16* __restrict__ Qb, const u16* __restrict__ Kb,
          const u16* __restrict__ Vt, u16* __restrict__ Ob) {
    __shared__ u16 Psm[4][32 * 68];
    int tid = threadIdx.x;
    int wave = tid >> 6, lane = tid & 63;
    int lr = lane & 15, lq = lane >> 4;
    int bh = blockIdx.y;
    int b = bh >> 4, h = bh & 15;
    int qbase = blockIdx.x * 128 + wave * 32;

    const u16* Qh = Qb + bh * 2048 * 64;
    const u16* Kh = Kb + bh * 2048 * 64;
    const u16* Vh = Vt + bh * 64 * 2048;

    bf16x8 qf[2][2];
    for (int s = 0; s < 2; s++)
        for (int hf = 0; hf < 2; hf++)
            qf[s][hf] = ldfrag(Qh + (qbase + s * 16 + lr) * 64 + hf * 32 + lq * 8);

    __bf16 one = (__bf16)1.0f;
    bf16x8 onef = {one, one, one, one, one, one, one, one};

    f32x4 o[2][4], l5[2];
    for (int s = 0; s < 2; s++) {
        l5[s] = (f32x4){0.f, 0.f, 0.f, 0.f};
        for (int dt = 0; dt < 4; dt++) o[s][dt] = (f32x4){0.f, 0.f, 0.f, 0.f};
    }

    // K B-frag: key = kv + kg*16 + lr, d = hf*32 + lq*8  (16B/lane, coalesced rows)
    const u16* kb = Kh + lr * 64 + lq * 8;
    // V A-frag (swapped PV): d = dt*16 + lr, key = kv + kc*32 + lq*8
    const u16* vb = Vh + lr * 2048 + lq * 8;

    u16* pwr0 = &Psm[wave][(lq * 4) * 68 + lr];
    u16* pwr1 = &Psm[wave][(16 + lq * 4) * 68 + lr];

    for (int kv = 0; kv < 2048; kv += 64) {
        u16x8 kf[4][2], vf[4][2];
        for (int kg = 0; kg < 4; kg++)
            for (int hf = 0; hf < 2; hf++)
                kf[kg][hf] = *(const u16x8*)(kb + (kv + kg * 16) * 64 + hf * 32);
        for (int dt = 0; dt < 4; dt++)
            for (int kc = 0; kc < 2; kc++)
                vf[dt][kc] = *(const u16x8*)(vb + dt * 16 * 2048 + kv + kc * 32);

        // S = Q K^T per key-group; exp + P-store immediately (short sc lifetime)
        for (int kg = 0; kg < 4; kg++) {
            for (int s = 0; s < 2; s++) {
                f32x4 a = (f32x4){0.f, 0.f, 0.f, 0.f};
                a = __builtin_amdgcn_mfma_f32_16x16x32_bf16(qf[s][0], asbf(kf[kg][0]), a, 0, 0, 0);
                a = __builtin_amdgcn_mfma_f32_16x16x32_bf16(qf[s][1], asbf(kf[kg][1]), a, 0, 0, 0);
                u16* pw = s ? pwr1 : pwr0;
                for (int r = 0; r < 4; r++) {
                    float pv = __builtin_amdgcn_exp2f(a[r]);
                    unsigned u = __float_as_uint(pv) + 0x8000u;
                    pw[r * 68 + kg * 16] = (u16)(u >> 16);
                }
            }
        }
        asm volatile("s_waitcnt lgkmcnt(0)" ::: "memory");  // wave-local P visibility

        // O^T += V^T P^T ; l via ones-mfma (all per-wave: NO barrier)
        for (int s = 0; s < 2; s++) {
            for (int kc = 0; kc < 2; kc++) {
                bf16x8 pf = ldfrag(&Psm[wave][(s * 16 + lr) * 68 + kc * 32 + lq * 8]);
                for (int dt = 0; dt < 4; dt++)
                    o[s][dt] = __builtin_amdgcn_mfma_f32_16x16x32_bf16(asbf(vf[dt][kc]), pf, o[s][dt], 0, 0, 0);
                l5[s] = __builtin_amdgcn_mfma_f32_16x16x32_bf16(onef, pf, l5[s], 0, 0, 0);
            }
        }
    }

    for (int s = 0; s < 2; s++) {
        float linv = 1.0f / l5[s][0];
        int q = qbase + s * 16 + lr;
        u16* obase = Ob + (b * 2048 + q) * 1024 + h * 64 + lq * 4;
        for (int dt = 0; dt < 4; dt++) {
            uint2 w = pack4(o[s][dt][0] * linv, o[s][dt][1] * linv,
                            o[s][dt][2] * linv, o[s][dt][3] * linv);
            *(uint2*)(obase + dt * 16) = w;
        }
    }
}

// ---------------- launch ----------------

extern "C" void kernel_launch(void* const* d_in, const int* in_sizes, int n_in,
                              void* d_out, int out_size, void* d_ws, size_t ws_size,
                              hipStream_t stream) {
    const float* x  = (const float*)d_in[0];
    const float* Wq = (const float*)d_in[1];
    const float* bq = (const float*)d_in[2];
    const float* Wk = (const float*)d_in[3];
    const float* bk = (const float*)d_in[4];
    const float* Wv = (const float*)d_in[5];
    const float* bv = (const float*)d_in[6];
    const float* Wo = (const float*)d_in[7];
    const float* bo = (const float*)d_in[8];
    float* out = (float*)d_out;

    char* ws = (char*)d_ws;
    u16* xb    = (u16*)ws;                    // 16 MiB bf16 x; reused as attention output
    u16* Wt    = (u16*)(ws + (16u << 20));    // 6 MiB (Wq|Wk|Wv transposed, bf16)
    u16* Wot   = (u16*)(ws + (22u << 20));    // 2 MiB
    float* bqkv = (float*)(ws + (24u << 20)); // 12 KiB
    u16* Vtb   = (u16*)(ws + (25u << 20));    // 16 MiB [B,H,64,S]
    u16* Qb    = (u16*)d_out;                 // 16 MiB [B,H,S,64]  (d_out scratch)
    u16* Kb    = Qb + 4 * 16 * 2048 * 64;     // 16 MiB [B,H,S,64]  (d_out scratch)

    cvt_x<<<8192, 256, 0, stream>>>(x, xb, 8192 * 1024 / 4);
    dim3 tb(32, 32);
    transp<<<dim3(32, 32), tb, 0, stream>>>(Wq, Wt);
    transp<<<dim3(32, 32), tb, 0, stream>>>(Wk, Wt + 1024 * 1024);
    transp<<<dim3(32, 32), tb, 0, stream>>>(Wv, Wt + 2 * 1024 * 1024);
    transp<<<dim3(32, 32), tb, 0, stream>>>(Wo, Wot);
    mkbias<<<12, 256, 0, stream>>>(bq, bk, bv, bqkv);

    gemm128<0><<<dim3(16, 64), 256, 0, stream>>>(xb, Wt, bqkv, Qb, Kb, nullptr, nullptr);
    gemm128<1><<<dim3(8, 64), 256, 0, stream>>>(xb, Wt + 2048 * 1024, bqkv + 2048,
                                                nullptr, nullptr, Vtb, nullptr);
    attn<<<dim3(16, 64), 256, 0, stream>>>(Qb, Kb, Vtb, xb);
    gemm128<2><<<dim3(8, 64), 256, 0, stream>>>(xb, Wot, bo, nullptr, nullptr, nullptr, out);
}

// Round 6
// 353.905 us; speedup vs baseline: 1.2601x; 1.2601x over previous
//
#include <hip/hip_runtime.h>

typedef unsigned short u16;
typedef unsigned int u32;
typedef unsigned short u16x8 __attribute__((ext_vector_type(8)));
typedef __bf16 bf16x8 __attribute__((ext_vector_type(8)));
typedef float f32x4 __attribute__((ext_vector_type(4)));

#define QSCALE 0.18033688011112042f  /* 0.125 * log2(e) */

__device__ __forceinline__ u16 f2bf(float f) {
    unsigned u = __float_as_uint(f);
    u += 0x7fffu + ((u >> 16) & 1u);
    return (u16)(u >> 16);
}

__device__ __forceinline__ bf16x8 ldfrag(const u16* p) {
    return __builtin_bit_cast(bf16x8, *(const u16x8*)p);
}

__device__ __forceinline__ void async_cp16(const void* g, void* l) {
    __builtin_amdgcn_global_load_lds(
        (const __attribute__((address_space(1))) unsigned int*)g,
        (__attribute__((address_space(3))) unsigned int*)l, 16, 0, 0);
}

__device__ __forceinline__ uint2 pack4(float a, float b, float c, float d) {
    uint2 w;
    w.x = (u32)f2bf(a) | ((u32)f2bf(b) << 16);
    w.y = (u32)f2bf(c) | ((u32)f2bf(d) << 16);
    return w;
}

// ---------------- conversion kernels ----------------

__global__ void cvt_x(const float* __restrict__ x, u16* __restrict__ xb, int n4) {
    int i = blockIdx.x * blockDim.x + threadIdx.x;
    if (i < n4) {
        float4 v = ((const float4*)x)[i];
        ushort4 o;
        o.x = f2bf(v.x); o.y = f2bf(v.y); o.z = f2bf(v.z); o.w = f2bf(v.w);
        ((ushort4*)xb)[i] = o;
    }
}

__global__ __launch_bounds__(1024) void transp(const float* __restrict__ src, u16* __restrict__ dst) {
    __shared__ float t[32][33];
    int bx = blockIdx.x * 32, by = blockIdx.y * 32;
    t[threadIdx.y][threadIdx.x] = src[(by + threadIdx.y) * 1024 + bx + threadIdx.x];
    __syncthreads();
    dst[(bx + threadIdx.y) * 1024 + by + threadIdx.x] = f2bf(t[threadIdx.x][threadIdx.y]);
}

__global__ void mkbias(const float* __restrict__ bq, const float* __restrict__ bk,
                       const float* __restrict__ bv, float* __restrict__ bqkv) {
    int i = blockIdx.x * blockDim.x + threadIdx.x;
    if (i < 3072) bqkv[i] = (i < 1024) ? bq[i] : (i < 2048 ? bk[i - 1024] : bv[i - 2048]);
}

// ---------------- GEMM: C[M,N] = A[M,K] * Bt[N,K]^T + bias ----------------
// BK=64, unpadded [128][64] LDS tiles with XOR swizzle (group ^= row&7):
// conflict-free b128 frag reads, lane-contiguous global_load_lds staging,
// 32 MFMA per barrier-pair.
// EPI 0: Q/K projection, swapped mfma (C^T) -> packed dwordx2 to Qb/Kb
// EPI 1: V projection, normal operands -> packed dwordx2 to Vt [bh][dh][s]
// EPI 2: output projection, swapped -> float4 to outf

template <int EPI>
__global__ __launch_bounds__(256)
void gemm128(const u16* __restrict__ A, const u16* __restrict__ Bt,
             const float* __restrict__ bias,
             u16* __restrict__ Qb, u16* __restrict__ Kb, u16* __restrict__ Vt,
             float* __restrict__ outf) {
    __shared__ u16 Asm[128 * 64];
    __shared__ u16 Bsm[128 * 64];
    int tid = threadIdx.x;
    int wave = tid >> 6, lane = tid & 63;
    int lr = lane & 15, lq = lane >> 4;
    int wrow = (wave >> 1) * 64, wcol = (wave & 1) * 64;
    int tileM = blockIdx.y * 128, tileN = blockIdx.x * 128;

    f32x4 acc[4][4];
    for (int i = 0; i < 4; i++)
        for (int j = 0; j < 4; j++)
            acc[i][j] = (f32x4){0.f, 0.f, 0.f, 0.f};

    int srow = tid >> 3;
    int sg = (tid & 7) ^ (srow & 7);
    const u16* ga = A + (tileM + srow) * 1024 + sg * 8;
    const u16* gb = Bt + (tileN + srow) * 1024 + sg * 8;
    u16* la = &Asm[tid * 8];
    u16* lb = &Bsm[tid * 8];

    int sw0 = ((lq ^ (lr & 7)) << 3);          // ko=0
    int sw1 = (((4 + lq) ^ (lr & 7)) << 3);    // ko=1

    for (int k0 = 0; k0 < 1024; k0 += 64) {
        for (int rnd = 0; rnd < 4; rnd++) {
            async_cp16(ga + k0 + rnd * 32 * 1024, la + rnd * 2048);
            async_cp16(gb + k0 + rnd * 32 * 1024, lb + rnd * 2048);
        }
        __syncthreads();
        for (int ko = 0; ko < 2; ko++) {
            int sw = ko ? sw1 : sw0;
            bf16x8 af[4], bfr[4];
            for (int mt = 0; mt < 4; mt++) af[mt] = ldfrag(&Asm[(wrow + mt * 16 + lr) * 64 + sw]);
            for (int nt = 0; nt < 4; nt++) bfr[nt] = ldfrag(&Bsm[(wcol + nt * 16 + lr) * 64 + sw]);
            for (int mt = 0; mt < 4; mt++)
                for (int nt = 0; nt < 4; nt++) {
                    if (EPI == 1)
                        acc[mt][nt] = __builtin_amdgcn_mfma_f32_16x16x32_bf16(af[mt], bfr[nt], acc[mt][nt], 0, 0, 0);
                    else
                        acc[mt][nt] = __builtin_amdgcn_mfma_f32_16x16x32_bf16(bfr[nt], af[mt], acc[mt][nt], 0, 0, 0);
                }
        }
        __syncthreads();
    }

    if (EPI == 0) {
        for (int mt = 0; mt < 4; mt++) {
            int m = tileM + wrow + mt * 16 + lr;
            int b = m >> 11, s = m & 2047;
            for (int nt = 0; nt < 4; nt++) {
                int n0 = tileN + wcol + nt * 16 + lq * 4;   // [0,2048)
                float4 bn = *(const float4*)&bias[n0];
                int which = n0 >> 10, d = n0 & 1023, h = d >> 6, dh = d & 63;
                u16* dst = (which ? Kb : Qb) + ((b * 16 + h) * 2048 + s) * 64 + dh;
                f32x4 v = acc[mt][nt];
                uint2 w;
                if (which == 0)
                    w = pack4((v[0] + bn.x) * QSCALE, (v[1] + bn.y) * QSCALE,
                              (v[2] + bn.z) * QSCALE, (v[3] + bn.w) * QSCALE);
                else
                    w = pack4(v[0] + bn.x, v[1] + bn.y, v[2] + bn.z, v[3] + bn.w);
                *(uint2*)dst = w;
            }
        }
    } else if (EPI == 1) {
        for (int nt = 0; nt < 4; nt++) {
            int n0 = tileN + wcol + nt * 16 + lr;           // [0,1024) V-local
            float bn = bias[n0];                            // caller passed bias+2048
            int h = n0 >> 6, dh = n0 & 63;
            for (int mt = 0; mt < 4; mt++) {
                int m0 = tileM + wrow + mt * 16 + lq * 4;
                int b = m0 >> 11, s = m0 & 2047;
                f32x4 v = acc[mt][nt];
                uint2 w = pack4(v[0] + bn, v[1] + bn, v[2] + bn, v[3] + bn);
                *(uint2*)(Vt + ((b * 16 + h) * 64 + dh) * 2048 + s) = w;
            }
        }
    } else {
        for (int mt = 0; mt < 4; mt++) {
            int m = tileM + wrow + mt * 16 + lr;
            for (int nt = 0; nt < 4; nt++) {
                int n0 = tileN + wcol + nt * 16 + lq * 4;
                float4 bn = *(const float4*)&bias[n0];
                f32x4 v = acc[mt][nt];
                float4 st = {v[0] + bn.x, v[1] + bn.y, v[2] + bn.z, v[3] + bn.w};
                *(float4*)&outf[m * 1024 + n0] = st;
            }
        }
    }
}

// ---------------- flash attention ----------------
// r4 LDS-staged dbuf structure, but 32 queries/wave (128/block): the kernel is
// LDS-port-bound and K/V LDS reads are per-wave, so doubling queries/wave
// halves LDS bytes per query. QK^T computed transposed (swapped operands) so
// a lane owns 4 consecutive keys -> P stored with 8 ds_write_b64 instead of
// 32 ds_write_b16. l accumulated in VALU from exp registers (no ones-MFMA).
__global__ __launch_bounds__(256)
void attn(const u16* __restrict__ Qb, const u16* __restrict__ Kb,
          const u16* __restrict__ Vt, u16* __restrict__ Ob) {
    __shared__ u16 Ksm[2][64 * 64];
    __shared__ u16 Vsm[2][64 * 64];
    __shared__ u16 Psm[4][32 * 68];
    int tid = threadIdx.x;
    int wave = tid >> 6, lane = tid & 63;
    int lr = lane & 15, lq = lane >> 4;
    int bh = blockIdx.y;
    int b = bh >> 4, h = bh & 15;
    int qbase = blockIdx.x * 128 + wave * 32;

    const u16* Qh = Qb + bh * 2048 * 64;
    const u16* Kh = Kb + bh * 2048 * 64;
    const u16* Vh = Vt + bh * 64 * 2048;

    bf16x8 qf[2][2];
    for (int s = 0; s < 2; s++)
        for (int hf = 0; hf < 2; hf++)
            qf[s][hf] = ldfrag(Qh + (qbase + s * 16 + lr) * 64 + hf * 32 + lq * 8);

    f32x4 o[2][4];
    float lacc[2] = {0.f, 0.f};
    for (int s = 0; s < 2; s++)
        for (int dt = 0; dt < 4; dt++) o[s][dt] = (f32x4){0.f, 0.f, 0.f, 0.f};

    int sw0 = (lq ^ (lr & 7)) << 3;             // XOR-swizzled d-group (conflict-free b128)

    int sr = tid >> 3, sg = tid & 7;
    int ksw = ((sg ^ (sr & 7)) << 3);
    const u16* gk = Kh + sr * 64 + ksw;
    const u16* gv = Vh + sr * 2048 + ksw;

    u16* pw = &Psm[wave][lr * 68 + lq * 4];     // + s*16*68 + kg*16

    // prologue: stage tile 0 into buffer 0
    async_cp16(gk, &Ksm[0][tid * 8]);
    async_cp16(gk + 32 * 64, &Ksm[0][tid * 8 + 32 * 64]);
    async_cp16(gv, &Vsm[0][tid * 8]);
    async_cp16(gv + 32 * 2048, &Vsm[0][tid * 8 + 32 * 64]);

    for (int it = 0; it < 32; ++it) {
        int p = it & 1;
        __syncthreads();   // tile p DMA drained; all reads of buffer p^1 done

        if (it < 31) {     // stage next tile into p^1, overlapped with this iter
            gk += 64 * 64; gv += 64;
            async_cp16(gk, &Ksm[p ^ 1][tid * 8]);
            async_cp16(gk + 32 * 64, &Ksm[p ^ 1][tid * 8 + 32 * 64]);
            async_cp16(gv, &Vsm[p ^ 1][tid * 8]);
            async_cp16(gv + 32 * 2048, &Vsm[p ^ 1][tid * 8 + 32 * 64]);
        }

        // S^T = K Q^T (swapped): lane holds keys kg*16+lq*4+r, query lr
        for (int kg = 0; kg < 4; kg++) {
            const u16* krow = &Ksm[p][(kg * 16 + lr) * 64];
            bf16x8 kf0 = ldfrag(krow + sw0);
            bf16x8 kf1 = ldfrag(krow + (sw0 ^ 32));
            for (int s = 0; s < 2; s++) {
                f32x4 a = (f32x4){0.f, 0.f, 0.f, 0.f};
                a = __builtin_amdgcn_mfma_f32_16x16x32_bf16(kf0, qf[s][0], a, 0, 0, 0);
                a = __builtin_amdgcn_mfma_f32_16x16x32_bf16(kf1, qf[s][1], a, 0, 0, 0);
                float e0 = __builtin_amdgcn_exp2f(a[0]);
                float e1 = __builtin_amdgcn_exp2f(a[1]);
                float e2 = __builtin_amdgcn_exp2f(a[2]);
                float e3 = __builtin_amdgcn_exp2f(a[3]);
                lacc[s] += (e0 + e1) + (e2 + e3);
                *(uint2*)(pw + s * 16 * 68 + kg * 16) = pack4(e0, e1, e2, e3);
            }
        }
        asm volatile("s_waitcnt lgkmcnt(0)" ::: "memory");  // wave-local P visibility

        // O^T += V^T P^T (P^T read as B-frag from Psm[query][key])
        for (int kc = 0; kc < 2; kc++) {
            bf16x8 pf0 = ldfrag(&Psm[wave][lr * 68 + kc * 32 + lq * 8]);
            bf16x8 pf1 = ldfrag(&Psm[wave][(16 + lr) * 68 + kc * 32 + lq * 8]);
            for (int dt = 0; dt < 4; dt++) {
                bf16x8 vf = ldfrag(&Vsm[p][(dt * 16 + lr) * 64 + (sw0 ^ (kc << 5))]);
                o[0][dt] = __builtin_amdgcn_mfma_f32_16x16x32_bf16(vf, pf0, o[0][dt], 0, 0, 0);
                o[1][dt] = __builtin_amdgcn_mfma_f32_16x16x32_bf16(vf, pf1, o[1][dt], 0, 0, 0);
            }
        }
    }

    // reduce l over the 4 lq lanes of each query column
    for (int s = 0; s < 2; s++) {
        lacc[s] += __shfl_xor(lacc[s], 16);
        lacc[s] += __shfl_xor(lacc[s], 32);
    }

    // O^T C-layout: col = query = lr, rows = d = dt*16 + lq*4 + r
    for (int s = 0; s < 2; s++) {
        float linv = 1.0f / lacc[s];
        int q = qbase + s * 16 + lr;
        u16* obase = Ob + (b * 2048 + q) * 1024 + h * 64 + lq * 4;
        for (int dt = 0; dt < 4; dt++) {
            uint2 w = pack4(o[s][dt][0] * linv, o[s][dt][1] * linv,
                            o[s][dt][2] * linv, o[s][dt][3] * linv);
            *(uint2*)(obase + dt * 16) = w;
        }
    }
}

// ---------------- launch ----------------

extern "C" void kernel_launch(void* const* d_in, const int* in_sizes, int n_in,
                              void* d_out, int out_size, void* d_ws, size_t ws_size,
                              hipStream_t stream) {
    const float* x  = (const float*)d_in[0];
    const float* Wq = (const float*)d_in[1];
    const float* bq = (const float*)d_in[2];
    const float* Wk = (const float*)d_in[3];
    const float* bk = (const float*)d_in[4];
    const float* Wv = (const float*)d_in[5];
    const float* bv = (const float*)d_in[6];
    const float* Wo = (const float*)d_in[7];
    const float* bo = (const float*)d_in[8];
    float* out = (float*)d_out;

    char* ws = (char*)d_ws;
    u16* xb    = (u16*)ws;                    // 16 MiB bf16 x; reused as attention output
    u16* Wt    = (u16*)(ws + (16u << 20));    // 6 MiB (Wq|Wk|Wv transposed, bf16)
    u16* Wot   = (u16*)(ws + (22u << 20));    // 2 MiB
    float* bqkv = (float*)(ws + (24u << 20)); // 12 KiB
    u16* Vtb   = (u16*)(ws + (25u << 20));    // 16 MiB [B,H,64,S]
    u16* Qb    = (u16*)d_out;                 // 16 MiB [B,H,S,64]  (d_out scratch)
    u16* Kb    = Qb + 4 * 16 * 2048 * 64;     // 16 MiB [B,H,S,64]  (d_out scratch)

    cvt_x<<<8192, 256, 0, stream>>>(x, xb, 8192 * 1024 / 4);
    dim3 tb(32, 32);
    transp<<<dim3(32, 32), tb, 0, stream>>>(Wq, Wt);
    transp<<<dim3(32, 32), tb, 0, stream>>>(Wk, Wt + 1024 * 1024);
    transp<<<dim3(32, 32), tb, 0, stream>>>(Wv, Wt + 2 * 1024 * 1024);
    transp<<<dim3(32, 32), tb, 0, stream>>>(Wo, Wot);
    mkbias<<<12, 256, 0, stream>>>(bq, bk, bv, bqkv);

    gemm128<0><<<dim3(16, 64), 256, 0, stream>>>(xb, Wt, bqkv, Qb, Kb, nullptr, nullptr);
    gemm128<1><<<dim3(8, 64), 256, 0, stream>>>(xb, Wt + 2048 * 1024, bqkv + 2048,
                                                nullptr, nullptr, Vtb, nullptr);
    attn<<<dim3(16, 64), 256, 0, stream>>>(Qb, Kb, Vtb, xb);
    gemm128<2><<<dim3(8, 64), 256, 0, stream>>>(xb, Wot, bo, nullptr, nullptr, nullptr, out);
}

// Round 8
// 332.015 us; speedup vs baseline: 1.3432x; 1.0659x over previous
//
#include <hip/hip_runtime.h>

typedef unsigned short u16;
typedef unsigned int u32;
typedef unsigned short u16x8 __attribute__((ext_vector_type(8)));
typedef short s16x4 __attribute__((ext_vector_type(4)));
typedef __bf16 bf16x8 __attribute__((ext_vector_type(8)));
typedef float f32x4 __attribute__((ext_vector_type(4)));

#define QSCALE 0.18033688011112042f  /* 0.125 * log2(e) */

__device__ __forceinline__ u16 f2bf(float f) {
    unsigned u = __float_as_uint(f);
    u += 0x7fffu + ((u >> 16) & 1u);
    return (u16)(u >> 16);
}

__device__ __forceinline__ bf16x8 ldfrag(const u16* p) {
    return __builtin_bit_cast(bf16x8, *(const u16x8*)p);
}

__device__ __forceinline__ void async_cp16(const void* g, void* l) {
    __builtin_amdgcn_global_load_lds(
        (const __attribute__((address_space(1))) unsigned int*)g,
        (__attribute__((address_space(3))) unsigned int*)l, 16, 0, 0);
}

__device__ __forceinline__ uint2 pack4(float a, float b, float c, float d) {
    uint2 w;
    w.x = (u32)f2bf(a) | ((u32)f2bf(b) << 16);
    w.y = (u32)f2bf(c) | ((u32)f2bf(d) << 16);
    return w;
}

// 16x16x16 bf16 MFMA (K=16): B-operand lane layout (n=lane&15, k=lq*4+j)
// exactly matches the 16x16 C/D layout (col=lane&15, row=lq*4+reg), letting
// the softmax'd scores feed PV with NO cross-lane/LDS transform.
__device__ __forceinline__ f32x4 mfma16(uint2 a, uint2 b, f32x4 c) {
#if __has_builtin(__builtin_amdgcn_mfma_f32_16x16x16bf16_1k)
    return __builtin_amdgcn_mfma_f32_16x16x16bf16_1k(
        __builtin_bit_cast(s16x4, a), __builtin_bit_cast(s16x4, b), c, 0, 0, 0);
#else
    asm volatile("s_nop 1\n\tv_mfma_f32_16x16x16_bf16 %0, %1, %2, %0"
                 : "+v"(c) : "v"(a), "v"(b));
    return c;
#endif
}

// ---------------- conversion kernels ----------------

__global__ void cvt_x(const float* __restrict__ x, u16* __restrict__ xb, int n4) {
    int i = blockIdx.x * blockDim.x + threadIdx.x;
    if (i < n4) {
        float4 v = ((const float4*)x)[i];
        ushort4 o;
        o.x = f2bf(v.x); o.y = f2bf(v.y); o.z = f2bf(v.z); o.w = f2bf(v.w);
        ((ushort4*)xb)[i] = o;
    }
}

__global__ __launch_bounds__(1024) void transp(const float* __restrict__ src, u16* __restrict__ dst) {
    __shared__ float t[32][33];
    int bx = blockIdx.x * 32, by = blockIdx.y * 32;
    t[threadIdx.y][threadIdx.x] = src[(by + threadIdx.y) * 1024 + bx + threadIdx.x];
    __syncthreads();
    dst[(bx + threadIdx.y) * 1024 + by + threadIdx.x] = f2bf(t[threadIdx.x][threadIdx.y]);
}

__global__ void mkbias(const float* __restrict__ bq, const float* __restrict__ bk,
                       const float* __restrict__ bv, float* __restrict__ bqkv) {
    int i = blockIdx.x * blockDim.x + threadIdx.x;
    if (i < 3072) bqkv[i] = (i < 1024) ? bq[i] : (i < 2048 ? bk[i - 1024] : bv[i - 2048]);
}

// ---------------- GEMM: C[M,N] = A[M,K] * Bt[N,K]^T + bias ----------------
// (unchanged from r6: BK=64, XOR-swizzled unpadded LDS, 32 MFMA/barrier-pair)

template <int EPI>
__global__ __launch_bounds__(256)
void gemm128(const u16* __restrict__ A, const u16* __restrict__ Bt,
             const float* __restrict__ bias,
             u16* __restrict__ Qb, u16* __restrict__ Kb, u16* __restrict__ Vt,
             float* __restrict__ outf) {
    __shared__ u16 Asm[128 * 64];
    __shared__ u16 Bsm[128 * 64];
    int tid = threadIdx.x;
    int wave = tid >> 6, lane = tid & 63;
    int lr = lane & 15, lq = lane >> 4;
    int wrow = (wave >> 1) * 64, wcol = (wave & 1) * 64;
    int tileM = blockIdx.y * 128, tileN = blockIdx.x * 128;

    f32x4 acc[4][4];
    for (int i = 0; i < 4; i++)
        for (int j = 0; j < 4; j++)
            acc[i][j] = (f32x4){0.f, 0.f, 0.f, 0.f};

    int srow = tid >> 3;
    int sg = (tid & 7) ^ (srow & 7);
    const u16* ga = A + (tileM + srow) * 1024 + sg * 8;
    const u16* gb = Bt + (tileN + srow) * 1024 + sg * 8;
    u16* la = &Asm[tid * 8];
    u16* lb = &Bsm[tid * 8];

    int sw0 = ((lq ^ (lr & 7)) << 3);
    int sw1 = (((4 + lq) ^ (lr & 7)) << 3);

    for (int k0 = 0; k0 < 1024; k0 += 64) {
        for (int rnd = 0; rnd < 4; rnd++) {
            async_cp16(ga + k0 + rnd * 32 * 1024, la + rnd * 2048);
            async_cp16(gb + k0 + rnd * 32 * 1024, lb + rnd * 2048);
        }
        __syncthreads();
        for (int ko = 0; ko < 2; ko++) {
            int sw = ko ? sw1 : sw0;
            bf16x8 af[4], bfr[4];
            for (int mt = 0; mt < 4; mt++) af[mt] = ldfrag(&Asm[(wrow + mt * 16 + lr) * 64 + sw]);
            for (int nt = 0; nt < 4; nt++) bfr[nt] = ldfrag(&Bsm[(wcol + nt * 16 + lr) * 64 + sw]);
            for (int mt = 0; mt < 4; mt++)
                for (int nt = 0; nt < 4; nt++) {
                    if (EPI == 1)
                        acc[mt][nt] = __builtin_amdgcn_mfma_f32_16x16x32_bf16(af[mt], bfr[nt], acc[mt][nt], 0, 0, 0);
                    else
                        acc[mt][nt] = __builtin_amdgcn_mfma_f32_16x16x32_bf16(bfr[nt], af[mt], acc[mt][nt], 0, 0, 0);
                }
        }
        __syncthreads();
    }

    if (EPI == 0) {
        for (int mt = 0; mt < 4; mt++) {
            int m = tileM + wrow + mt * 16 + lr;
            int b = m >> 11, s = m & 2047;
            for (int nt = 0; nt < 4; nt++) {
                int n0 = tileN + wcol + nt * 16 + lq * 4;   // [0,2048)
                float4 bn = *(const float4*)&bias[n0];
                int which = n0 >> 10, d = n0 & 1023, h = d >> 6, dh = d & 63;
                u16* dst = (which ? Kb : Qb) + ((b * 16 + h) * 2048 + s) * 64 + dh;
                f32x4 v = acc[mt][nt];
                uint2 w;
                if (which == 0)
                    w = pack4((v[0] + bn.x) * QSCALE, (v[1] + bn.y) * QSCALE,
                              (v[2] + bn.z) * QSCALE, (v[3] + bn.w) * QSCALE);
                else
                    w = pack4(v[0] + bn.x, v[1] + bn.y, v[2] + bn.z, v[3] + bn.w);
                *(uint2*)dst = w;
            }
        }
    } else if (EPI == 1) {
        for (int nt = 0; nt < 4; nt++) {
            int n0 = tileN + wcol + nt * 16 + lr;           // [0,1024) V-local
            float bn = bias[n0];                            // caller passed bias+2048
            int h = n0 >> 6, dh = n0 & 63;
            for (int mt = 0; mt < 4; mt++) {
                int m0 = tileM + wrow + mt * 16 + lq * 4;
                int b = m0 >> 11, s = m0 & 2047;
                f32x4 v = acc[mt][nt];
                uint2 w = pack4(v[0] + bn, v[1] + bn, v[2] + bn, v[3] + bn);
                *(uint2*)(Vt + ((b * 16 + h) * 64 + dh) * 2048 + s) = w;
            }
        }
    } else {
        for (int mt = 0; mt < 4; mt++) {
            int m = tileM + wrow + mt * 16 + lr;
            for (int nt = 0; nt < 4; nt++) {
                int n0 = tileN + wcol + nt * 16 + lq * 4;
                float4 bn = *(const float4*)&bias[n0];
                f32x4 v = acc[mt][nt];
                float4 st = {v[0] + bn.x, v[1] + bn.y, v[2] + bn.z, v[3] + bn.w};
                *(float4*)&outf[m * 1024 + n0] = st;
            }
        }
    }
}

// ---------------- flash attention ----------------
// r6 structure (dbuf K/V, 1 barrier/iter, 32 q/wave) but P never touches LDS:
// S^T C-layout -> exp -> bf16-pair pack IS the 16x16x16 MFMA B-operand.
// LDS drops to 32.8KB (4 blocks/CU); no per-wave DS drain.
__global__ __launch_bounds__(256)
void attn(const u16* __restrict__ Qb, const u16* __restrict__ Kb,
          const u16* __restrict__ Vt, u16* __restrict__ Ob) {
    __shared__ u16 Ksm[2][64 * 64];
    __shared__ u16 Vsm[2][64 * 64];
    int tid = threadIdx.x;
    int wave = tid >> 6, lane = tid & 63;
    int lr = lane & 15, lq = lane >> 4;
    int bh = blockIdx.y;
    int b = bh >> 4, h = bh & 15;
    int qbase = blockIdx.x * 128 + wave * 32;

    const u16* Qh = Qb + bh * 2048 * 64;
    const u16* Kh = Kb + bh * 2048 * 64;
    const u16* Vh = Vt + bh * 64 * 2048;

    bf16x8 qf[2][2];
    for (int s = 0; s < 2; s++)
        for (int hf = 0; hf < 2; hf++)
            qf[s][hf] = ldfrag(Qh + (qbase + s * 16 + lr) * 64 + hf * 32 + lq * 8);

    f32x4 o[2][4];
    float lacc[2] = {0.f, 0.f};
    for (int s = 0; s < 2; s++)
        for (int dt = 0; dt < 4; dt++) o[s][dt] = (f32x4){0.f, 0.f, 0.f, 0.f};

    int sw0 = (lq ^ (lr & 7)) << 3;   // b128 K-frag swizzle (conflict-free)

    int sr = tid >> 3, sg = tid & 7;
    int ksw = ((sg ^ (sr & 7)) << 3);
    const u16* gk = Kh + sr * 64 + ksw;
    const u16* gv = Vh + sr * 2048 + ksw;

    // V b64-frag offset within row for key-group kg: keys kg*16 + lq*4 + j
    // linear grp = 2kg + (lq>>1), swizzled ^ (lr&7), + (lq&1)*4 elems
    int vsub = (lq & 1) * 4;
    int vx = (lq >> 1);

    // prologue: stage tile 0 into buffer 0
    async_cp16(gk, &Ksm[0][tid * 8]);
    async_cp16(gk + 32 * 64, &Ksm[0][tid * 8 + 32 * 64]);
    async_cp16(gv, &Vsm[0][tid * 8]);
    async_cp16(gv + 32 * 2048, &Vsm[0][tid * 8 + 32 * 64]);

    for (int it = 0; it < 32; ++it) {
        int p = it & 1;
        __syncthreads();   // tile p DMA drained; all reads of buffer p^1 done

        if (it < 31) {     // stage next tile into p^1, overlapped with this iter
            gk += 64 * 64; gv += 64;
            async_cp16(gk, &Ksm[p ^ 1][tid * 8]);
            async_cp16(gk + 32 * 64, &Ksm[p ^ 1][tid * 8 + 32 * 64]);
            async_cp16(gv, &Vsm[p ^ 1][tid * 8]);
            async_cp16(gv + 32 * 2048, &Vsm[p ^ 1][tid * 8 + 32 * 64]);
        }

        // S^T = K Q^T (swapped x32): lane holds (query=lr, keys kg*16+lq*4+r)
        uint2 pb[2][4];
        for (int kg = 0; kg < 4; kg++) {
            const u16* krow = &Ksm[p][(kg * 16 + lr) * 64];
            bf16x8 kf0 = ldfrag(krow + sw0);
            bf16x8 kf1 = ldfrag(krow + (sw0 ^ 32));
            for (int s = 0; s < 2; s++) {
                f32x4 a = (f32x4){0.f, 0.f, 0.f, 0.f};
                a = __builtin_amdgcn_mfma_f32_16x16x32_bf16(kf0, qf[s][0], a, 0, 0, 0);
                a = __builtin_amdgcn_mfma_f32_16x16x32_bf16(kf1, qf[s][1], a, 0, 0, 0);
                float e0 = __builtin_amdgcn_exp2f(a[0]);
                float e1 = __builtin_amdgcn_exp2f(a[1]);
                float e2 = __builtin_amdgcn_exp2f(a[2]);
                float e3 = __builtin_amdgcn_exp2f(a[3]);
                lacc[s] += (e0 + e1) + (e2 + e3);
                pb[s][kg] = pack4(e0, e1, e2, e3);
            }
        }

        // O^T += V^T P^T via 16x16x16 MFMA: pb is already the B-operand
        for (int kg = 0; kg < 4; kg++) {
            int vofs = (((2 * kg + vx) ^ (lr & 7)) << 3) + vsub;
            for (int dt = 0; dt < 4; dt++) {
                uint2 vf = *(const uint2*)&Vsm[p][(dt * 16 + lr) * 64 + vofs];
                o[0][dt] = mfma16(vf, pb[0][kg], o[0][dt]);
                o[1][dt] = mfma16(vf, pb[1][kg], o[1][dt]);
            }
        }
    }

    // reduce l over the 4 lq lanes of each query column
    for (int s = 0; s < 2; s++) {
        lacc[s] += __shfl_xor(lacc[s], 16);
        lacc[s] += __shfl_xor(lacc[s], 32);
    }

    // O^T C-layout: col = query = lr, rows = d = dt*16 + lq*4 + r
    for (int s = 0; s < 2; s++) {
        float linv = 1.0f / lacc[s];
        int q = qbase + s * 16 + lr;
        u16* obase = Ob + (b * 2048 + q) * 1024 + h * 64 + lq * 4;
        for (int dt = 0; dt < 4; dt++) {
            uint2 w = pack4(o[s][dt][0] * linv, o[s][dt][1] * linv,
                            o[s][dt][2] * linv, o[s][dt][3] * linv);
            *(uint2*)(obase + dt * 16) = w;
        }
    }
}

// ---------------- launch ----------------

extern "C" void kernel_launch(void* const* d_in, const int* in_sizes, int n_in,
                              void* d_out, int out_size, void* d_ws, size_t ws_size,
                              hipStream_t stream) {
    const float* x  = (const float*)d_in[0];
    const float* Wq = (const float*)d_in[1];
    const float* bq = (const float*)d_in[2];
    const float* Wk = (const float*)d_in[3];
    const float* bk = (const float*)d_in[4];
    const float* Wv = (const float*)d_in[5];
    const float* bv = (const float*)d_in[6];
    const float* Wo = (const float*)d_in[7];
    const float* bo = (const float*)d_in[8];
    float* out = (float*)d_out;

    char* ws = (char*)d_ws;
    u16* xb    = (u16*)ws;                    // 16 MiB bf16 x; reused as attention output
    u16* Wt    = (u16*)(ws + (16u << 20));    // 6 MiB (Wq|Wk|Wv transposed, bf16)
    u16* Wot   = (u16*)(ws + (22u << 20));    // 2 MiB
    float* bqkv = (float*)(ws + (24u << 20)); // 12 KiB
    u16* Vtb   = (u16*)(ws + (25u << 20));    // 16 MiB [B,H,64,S]
    u16* Qb    = (u16*)d_out;                 // 16 MiB [B,H,S,64]  (d_out scratch)
    u16* Kb    = Qb + 4 * 16 * 2048 * 64;     // 16 MiB [B,H,S,64]  (d_out scratch)

    cvt_x<<<8192, 256, 0, stream>>>(x, xb, 8192 * 1024 / 4);
    dim3 tb(32, 32);
    transp<<<dim3(32, 32), tb, 0, stream>>>(Wq, Wt);
    transp<<<dim3(32, 32), tb, 0, stream>>>(Wk, Wt + 1024 * 1024);
    transp<<<dim3(32, 32), tb, 0, stream>>>(Wv, Wt + 2 * 1024 * 1024);
    transp<<<dim3(32, 32), tb, 0, stream>>>(Wo, Wot);
    mkbias<<<12, 256, 0, stream>>>(bq, bk, bv, bqkv);

    gemm128<0><<<dim3(16, 64), 256, 0, stream>>>(xb, Wt, bqkv, Qb, Kb, nullptr, nullptr);
    gemm128<1><<<dim3(8, 64), 256, 0, stream>>>(xb, Wt + 2048 * 1024, bqkv + 2048,
                                                nullptr, nullptr, Vtb, nullptr);
    attn<<<dim3(16, 64), 256, 0, stream>>>(Qb, Kb, Vtb, xb);
    gemm128<2><<<dim3(8, 64), 256, 0, stream>>>(xb, Wot, bo, nullptr, nullptr, nullptr, out);
}